// Round 8
// baseline (67.253 us; speedup 1.0000x reference)
//
#include <hip/hip_runtime.h>
#include <hip/hip_bf16.h>
#include <cstdint>
#include <cstddef>

typedef __attribute__((ext_vector_type(8))) short bf16x8;
typedef __attribute__((ext_vector_type(4))) float f32x4;

#define BATCH 8
#define NTOK 8192
#define LDIM 512
#define DDIM 128
#define NQ 16
#define NSEG 8
#define SEGLEN (NTOK / NSEG) /* 1024 */

static __device__ __forceinline__ short f2bf(float f) {
  uint32_t u = __float_as_uint(f);
  uint32_t r = u + 0x7fffu + ((u >> 16) & 1u); // RNE
  return (short)(r >> 16);
}

// hardware packed f32->bf16 (RNE), 2 elements per instruction [T12: exists on gfx950]
static __device__ __forceinline__ bf16x8 cvt8(float4 a, float4 b) {
  union { uint32_t u[4]; bf16x8 v; } r;
  asm("v_cvt_pk_bf16_f32 %0, %1, %2" : "=v"(r.u[0]) : "v"(a.x), "v"(a.y));
  asm("v_cvt_pk_bf16_f32 %0, %1, %2" : "=v"(r.u[1]) : "v"(a.z), "v"(a.w));
  asm("v_cvt_pk_bf16_f32 %0, %1, %2" : "=v"(r.u[2]) : "v"(b.x), "v"(b.y));
  asm("v_cvt_pk_bf16_f32 %0, %1, %2" : "=v"(r.u[3]) : "v"(b.z), "v"(b.w));
  return r.v;
}

// pad-mask accessor robust to bool-ABI (byteFlag=1: 1B/elem, 0: int32/elem)
static __device__ __forceinline__ bool is_pad(const void* pad, int byteFlag, int j) {
  return byteFlag ? (((const unsigned char*)pad)[j] != 0)
                  : (((const int*)pad)[j] != 0);
}

// ---------------- k0: repack W1 -> MFMA B-frag order bf16; block 0 detects bool ABI ----------
// wfrag[(c*8 + t)*64 + lane][i] = bf16( W1[c*32 + (lane>>4)*8 + i][t*16 + (lane&15)] )
__global__ __launch_bounds__(256) void k0_wfrag(const float* __restrict__ W1,
                                                short* __restrict__ wfrag,
                                                const unsigned int* __restrict__ pad_raw,
                                                int* __restrict__ flag) {
  int tid = blockIdx.x * blockDim.x + threadIdx.x;
  if (tid < 16 * 8 * 64) {
    int l = tid & 63;
    int t = (tid >> 6) & 7;
    int c = tid >> 9;
    int kbase = c * 32 + (l >> 4) * 8;
    int col = t * 16 + (l & 15);
    bf16x8 frag;
#pragma unroll
    for (int i = 0; i < 8; ++i) frag[i] = f2bf(W1[(size_t)(kbase + i) * DDIM + col]);
    ((bf16x8*)wfrag)[tid] = frag;
  }
  if (blockIdx.x == 0) {
    int any_gt1 = 0;
    for (int i = threadIdx.x; i < 16384; i += 256)
      if (pad_raw[i] > 1u) any_gt1 = 1;
    unsigned long long m = __ballot(any_gt1);
    __shared__ int s[4];
    if ((threadIdx.x & 63) == 0) s[threadIdx.x >> 6] = (m != 0ull) ? 1 : 0;
    __syncthreads();
    if (threadIdx.x == 0) flag[0] = (s[0] | s[1] | s[2] | s[3]);
  }
}

// ---------------- k1: expw[row] = exp( tanh(x[row]W1)·W2 )  (no max needed: |A|<=~9) --------
// 512 thr (8 waves) x 16 rows/wave = 128 rows/block; grid 512; W1 in 4x32KB LDS quarters;
// x register-prefetched 6 chunks deep; hw cvt_pk for bf16.
__global__ __launch_bounds__(512, 4) void k1_scores(const float* __restrict__ x,
                                                    const short* __restrict__ wfrag,
                                                    const float* __restrict__ W2,
                                                    float* __restrict__ expw) {
  __shared__ short ldsw[16384]; // 32 KB: one quarter of wfrag (4 K-chunks)
  const int tid = threadIdx.x, wave = tid >> 6, lane = tid & 63;
  const int rowBase = blockIdx.x * 128 + wave * 16;
  const float* xp = x + (size_t)(rowBase + (lane & 15)) * LDIM + ((lane >> 4) * 8);

// stage 32KB quarter qd of wfrag into LDS (512 thr x 4 x 16B), linear dest
#define STAGE(qd)                                                                             \
  {                                                                                           \
    const unsigned int* src_ = (const unsigned int*)wfrag + (qd) * 8192;                      \
    _Pragma("unroll")                                                                         \
    for (int i = 0; i < 4; ++i) {                                                             \
      __builtin_amdgcn_global_load_lds(                                                       \
          (const __attribute__((address_space(1))) unsigned int*)(src_ + (i * 512 + tid) * 4),\
          (__attribute__((address_space(3))) unsigned int*)&ldsw[(i * 512 + wave * 64) * 8],  \
          16, 0, 0);                                                                          \
    }                                                                                         \
  }

#define ALOAD(dst, c)                                  \
  {                                                    \
    dst[0] = *(const float4*)(xp + (c) * 32);          \
    dst[1] = *(const float4*)(xp + (c) * 32 + 4);      \
  }

  f32x4 acc[8];
#pragma unroll
  for (int t = 0; t < 8; ++t) acc[t] = (f32x4){0.f, 0.f, 0.f, 0.f};
  float4 avbuf[6][2]; // 6 chunks of x in flight

  STAGE(0);
  ALOAD(avbuf[0], 0);
  ALOAD(avbuf[1], 1);
  ALOAD(avbuf[2], 2);
  ALOAD(avbuf[3], 3);
  ALOAD(avbuf[4], 4);
  ALOAD(avbuf[5], 5);
  __syncthreads(); // stage-0 landed

#pragma unroll
  for (int qd = 0; qd < 4; ++qd) {
#pragma unroll
    for (int cc = 0; cc < 4; ++cc) {
      const int c = qd * 4 + cc;
      bf16x8 af = cvt8(avbuf[c % 6][0], avbuf[c % 6][1]);
      if (c < 10) ALOAD(avbuf[c % 6], c + 6); // keep 6 chunks of x in flight
#pragma unroll
      for (int t = 0; t < 8; ++t) {
        bf16x8 bfr = *(const bf16x8*)&ldsw[((cc * 8 + t) * 64 + lane) * 8];
        acc[t] = __builtin_amdgcn_mfma_f32_16x16x32_bf16(af, bfr, acc[t], 0, 0, 0);
      }
    }
    if (qd < 3) {
      __syncthreads(); // all waves done reading quarter qd
      STAGE(qd + 1);
      __syncthreads(); // quarter qd+1 landed
    }
  }
#undef STAGE
#undef ALOAD

  // epilogue: tanh + dot W2 + 16-lane reduce; D layout col=lane&15(+16t), row=(lane>>4)*4+r
  float w2v[8];
#pragma unroll
  for (int t = 0; t < 8; ++t) w2v[t] = W2[t * 16 + (lane & 15)];
  float asum[4] = {0.f, 0.f, 0.f, 0.f};
#pragma unroll
  for (int t = 0; t < 8; ++t) {
#pragma unroll
    for (int r = 0; r < 4; ++r) {
      float h = 1.f - 2.f / (__expf(2.f * acc[t][r]) + 1.f); // tanh
      asum[r] += h * w2v[t];
    }
  }
#pragma unroll
  for (int m = 1; m < 16; m <<= 1) {
#pragma unroll
    for (int r = 0; r < 4; ++r) asum[r] += __shfl_xor(asum[r], m, 64);
  }
  if ((lane & 15) == 0) {
    int rb = rowBase + (lane >> 4) * 4;
#pragma unroll
    for (int r = 0; r < 4; ++r) expw[rb + r] = __expf(asum[r]); // unnormalized weight
  }
}

// ---------------- k3: pooling partials; register-carried compaction, 4x128 float4 accum ----
// grid ((b*16+q)*8+s) = 1024 blocks x 512 thr.
__global__ __launch_bounds__(512) void k3_pool(const float* __restrict__ x,
                                               const float* __restrict__ expw,
                                               const int* __restrict__ ids,
                                               const void* __restrict__ pad,
                                               const int* __restrict__ flag,
                                               float* __restrict__ partial,
                                               float* __restrict__ wsum) {
  int blk = blockIdx.x;
  int s = blk & 7, q = (blk >> 3) & 15, b = blk >> 7;
  int wave = threadIdx.x >> 6, lane = threadIdx.x & 63;
  int bfl = flag[0];
  __shared__ float w_u[1024];
  __shared__ unsigned short j_u[1024];
  __shared__ int cnt[8];
  __shared__ float wred[8];

  const int base = b * NTOK;
  const int tokBase = s * SEGLEN + wave * 128;

  // membership + weights, carried in registers across the count-sync
  int j0 = tokBase + lane, j1 = tokBase + 64 + lane;
  bool mem0 = (ids[base + j0] == q) && !is_pad(pad, bfl, base + j0);
  bool mem1 = (ids[base + j1] == q) && !is_pad(pad, bfl, base + j1);
  float wt0 = mem0 ? expw[base + j0] : 0.f;
  float wt1 = mem1 ? expw[base + j1] : 0.f;
  unsigned long long m0 = __ballot(mem0), m1 = __ballot(mem1);
  int c0w = __popcll(m0), c1w = __popcll(m1);
  if (lane == 0) cnt[wave] = c0w + c1w;
  __syncthreads();

  int wpos = 0;
#pragma unroll
  for (int w = 0; w < 8; ++w) if (w < wave) wpos += cnt[w];
  const int total = cnt[0] + cnt[1] + cnt[2] + cnt[3] + cnt[4] + cnt[5] + cnt[6] + cnt[7];

  unsigned long long below = (1ull << lane) - 1ull;
  if (mem0) {
    int pos = wpos + __popcll(m0 & below);
    w_u[pos] = wt0; j_u[pos] = (unsigned short)j0;
  }
  if (mem1) {
    int pos = wpos + c0w + __popcll(m1 & below);
    w_u[pos] = wt1; j_u[pos] = (unsigned short)j1;
  }
  float wacc = wt0 + wt1;
#pragma unroll
  for (int m = 1; m < 64; m <<= 1) wacc += __shfl_xor(wacc, m, 64);
  if (lane == 0) wred[wave] = wacc;
  __syncthreads();

  // accumulate: group grp walks its quarter of entries; 128 threads x float4 = 512 cols
  int grp = threadIdx.x >> 7, ct = threadIdx.x & 127;
  int c0 = ct * 4;
  int per = (total + 3) >> 2;
  int e0 = grp * per;
  int e1 = e0 + per; if (e1 > total) e1 = total;
  float4 av = {0.f, 0.f, 0.f, 0.f};
  if (e0 < e1) {
    float4 cur = *(const float4*)(x + (size_t)(base + j_u[e0]) * LDIM + c0);
    int e = e0;
    for (; e + 1 < e1; ++e) {
      float4 nxt = *(const float4*)(x + (size_t)(base + j_u[e + 1]) * LDIM + c0); // load-ahead
      float wt = w_u[e];
      av.x = fmaf(wt, cur.x, av.x); av.y = fmaf(wt, cur.y, av.y);
      av.z = fmaf(wt, cur.z, av.z); av.w = fmaf(wt, cur.w, av.w);
      cur = nxt;
    }
    float wt = w_u[e];
    av.x = fmaf(wt, cur.x, av.x); av.y = fmaf(wt, cur.y, av.y);
    av.z = fmaf(wt, cur.z, av.z); av.w = fmaf(wt, cur.w, av.w);
  }
  *(float4*)(partial + ((size_t)(blk * 4 + grp)) * LDIM + c0) = av;
  if (threadIdx.x == 0)
    wsum[blk] = wred[0] + wred[1] + wred[2] + wred[3] + wred[4] + wred[5] + wred[6] + wred[7];
}

// ---------------- k4: combine 32 partial slots per (b,q) + normalize ----------------
__global__ __launch_bounds__(512) void k4_reduce(const float* __restrict__ partial,
                                                 const float* __restrict__ wsum,
                                                 float* __restrict__ out) {
  int bq = blockIdx.x; // b*16+q
  int b = bq >> 4, q = bq & 15;
  int c = threadIdx.x;
  float ws = 0.f;
#pragma unroll
  for (int s = 0; s < 8; ++s) ws += wsum[b * 128 + q * 8 + s];
  float ps = 0.f;
#pragma unroll
  for (int s = 0; s < 8; ++s)
#pragma unroll
    for (int g = 0; g < 4; ++g)
      ps += partial[((size_t)((b * 128 + q * 8 + s) * 4 + g)) * LDIM + c];
  out[bq * 512 + c] = (ws > 0.f) ? (ps / ws) : 0.f;
}

extern "C" void kernel_launch(void* const* d_in, const int* in_sizes, int n_in,
                              void* d_out, int out_size, void* d_ws, size_t ws_size,
                              hipStream_t stream) {
  const float* x = (const float*)d_in[0];
  const float* W1 = (const float*)d_in[1];
  const float* W2 = (const float*)d_in[2];
  const int* ids = (const int*)d_in[3];
  const void* pad = d_in[4]; // bool ABI detected at runtime
  float* out = (float*)d_out;

  char* ws = (char*)d_ws;
  short* wfrag = (short*)ws;                 // 131072 B
  int* flag = (int*)(ws + 131072);           // 4 B
  float* expw = (float*)(ws + 131200);       // 262144 B
  float* wsum = (float*)(ws + 393344);       // 4096 B
  float* partial = (float*)(ws + 397440);    // 1024*4*512*4 = 8388608 B

  hipLaunchKernelGGL(k0_wfrag, dim3(32), dim3(256), 0, stream,
                     W1, wfrag, (const unsigned int*)pad, flag);
  hipLaunchKernelGGL(k1_scores, dim3((BATCH * NTOK) / 128), dim3(512), 0, stream,
                     x, wfrag, W2, expw);
  hipLaunchKernelGGL(k3_pool, dim3(BATCH * NQ * NSEG), dim3(512), 0, stream,
                     x, expw, ids, pad, flag, partial, wsum);
  hipLaunchKernelGGL(k4_reduce, dim3(BATCH * NQ), dim3(512), 0, stream,
                     partial, wsum, out);
}